// Round 11
// baseline (80.801 us; speedup 1.0000x reference)
//
#include <hip/hip_runtime.h>

// Problem constants (match reference)
#define HH 256
#define WW 256
#define NPIX (HH * WW)        // 65536
#define NP 512                // points
// ALPHA = -5.0, 1/ALPHA = -0.2

// Homogeneous-cost grid: all blocks ~2000-2600 issue-cycles.
// t1: 512 blocks x 128 pixels, thread pairs split the 512-point scan.
// t2: 1024 blocks = 128 point-groups (PPB=4) x 8 row-slices.
#define PPB 4
#define SLICE_ROWS 32
#define NSLICES (HH / SLICE_ROWS)          // 8
#define NPGRP (NP / PPB)                   // 128
#define NB_T2 (NPGRP * NSLICES)            // 1024
#define NB_T1 512                          // 128 pixels each
#define NB_TOTAL (NB_T1 + NB_T2)           // 1536 = exactly 6 blocks/CU

// ws float layout (NO memset: every slot read by final is written by main):
//   [0 .. 4096)          S-partials: ws[p*8 + slice]
//   [4096 .. 4608)       term1 v1 partials (per t1 block)
//   [4608 .. 5120)       term1 v2 partials
#define WS_SP   0
#define WS_T1A  4096
#define WS_T1B  (WS_T1A + NB_T1)           // 4608

// launch_bounds(256, 6): 6 blocks/CU co-resident (grid = 6/CU exactly);
// VGPR cap ~85 keeps the prefetch registers live (default allocator had
// crushed to 44 VGPRs and re-sunk the loads into the loop).
__global__ __launch_bounds__(256, 6) void whd_main(const float* __restrict__ hm,
                                                   const float* __restrict__ pts,
                                                   float* __restrict__ ws) {
    const int tid = threadIdx.x;
    const int bid = blockIdx.x;
    __shared__ float sred[PPB][4];
    __shared__ float dmax_sh;

    if (bid < NB_T1) {
        // -------- term 1: 128 pixels/block; lane pairs split the 512 points --------
        const int pix  = bid * 128 + (tid >> 1);   // pixel index
        const int half = tid & 1;                  // which 256-point half
        const float fi = (float)(pix >> 8);
        const float fj = (float)(pix & (WW - 1));
        const float4* pts4 = (const float4*)pts;
        const int base = half * 128;               // float4 offset for this half
        float m0 = 3.4e38f, m1 = 3.4e38f, m2 = 3.4e38f, m3 = 3.4e38f;
        #pragma unroll 4
        for (int i = 0; i < 128; i += 4) {         // 32 iters x 8 points
            float4 q0 = pts4[base + i],     q1 = pts4[base + i + 1];
            float4 q2 = pts4[base + i + 2], q3 = pts4[base + i + 3];
            float dy, dx;
            dy = fi - q0.x; dx = fj - q0.y; m0 = fminf(m0, fmaf(dy, dy, dx * dx));
            dy = fi - q0.z; dx = fj - q0.w; m1 = fminf(m1, fmaf(dy, dy, dx * dx));
            dy = fi - q1.x; dx = fj - q1.y; m2 = fminf(m2, fmaf(dy, dy, dx * dx));
            dy = fi - q1.z; dx = fj - q1.w; m3 = fminf(m3, fmaf(dy, dy, dx * dx));
            dy = fi - q2.x; dx = fj - q2.y; m0 = fminf(m0, fmaf(dy, dy, dx * dx));
            dy = fi - q2.z; dx = fj - q2.w; m1 = fminf(m1, fmaf(dy, dy, dx * dx));
            dy = fi - q3.x; dx = fj - q3.y; m2 = fminf(m2, fmaf(dy, dy, dx * dx));
            dy = fi - q3.z; dx = fj - q3.w; m3 = fminf(m3, fmaf(dy, dy, dx * dx));
        }
        float mm = fminf(fminf(m0, m1), fminf(m2, m3));
        mm = fminf(mm, __shfl_xor(mm, 1, 64));     // combine the two halves
        float mind = __builtin_amdgcn_sqrtf(mm);
        float h  = hm[pix];
        float v1 = (half == 0) ? h * mind : 0.f;   // count each pixel once
        float v2 = (half == 0) ? fabsf(h) : 0.f;
        #pragma unroll
        for (int off = 32; off; off >>= 1) {
            v1 += __shfl_down(v1, off, 64);
            v2 += __shfl_down(v2, off, 64);
        }
        if ((tid & 63) == 0) { sred[0][tid >> 6] = v1; sred[1][tid >> 6] = v2; }
        __syncthreads();
        if (tid == 0) ws[WS_T1A + bid] = sred[0][0] + sred[0][1] + sred[0][2] + sred[0][3];
        if (tid == 1) ws[WS_T1B + bid] = sred[1][0] + sred[1][1] + sred[1][2] + sred[1][3];
    } else {
        // ---------------- term 2: soft-min accumulation ----------------
        const int b2    = bid - NB_T1;
        const int pgrp  = b2 & (NPGRP - 1);
        const int slice = b2 >> 7;             // NPGRP = 128
        const int p0    = pgrp * PPB;

        // 2-deep hm prefetch pipeline; first two issued BEFORE the dmax
        // preamble so the preamble hides their L2 latency.
        const float4* hm4 = (const float4*)hm;
        const int gbase = slice * (SLICE_ROWS * WW / 4) + tid;
        float4 cur = hm4[gbase];
        float4 nxt = hm4[gbase + 256];

        // dmax by wave 0 only (grid max is at a corner; d^2 separable)
        if (tid < 64) {
            float m = 0.f;
            #pragma unroll
            for (int t = 0; t < 8; ++t) {
                int p = tid + t * 64;
                float py_ = pts[2 * p], px_ = pts[2 * p + 1];
                float my = fmaxf(py_ * py_, (255.f - py_) * (255.f - py_));
                float mx = fmaxf(px_ * px_, (255.f - px_) * (255.f - px_));
                m = fmaxf(m, my + mx);
            }
            #pragma unroll
            for (int off = 32; off; off >>= 1) m = fmaxf(m, __shfl_down(m, off, 64));
            if (tid == 0) dmax_sh = __builtin_amdgcn_sqrtf(m);
        }
        __syncthreads();
        const float dmax = dmax_sh;

        float py[PPB], px[PPB];
        #pragma unroll
        for (int a = 0; a < PPB; ++a) {        // uniform -> SGPR loads
            py[a] = pts[2 * (p0 + a)];
            px[a] = pts[2 * (p0 + a) + 1];
        }

        // thread owns cols col0..col0+3 of rows {slice*32 + (tid>>6) + 4k}
        const float col0 = (float)((tid & 63) << 2);
        float dx2[PPB][4];
        #pragma unroll
        for (int a = 0; a < PPB; ++a)
            #pragma unroll
            for (int c = 0; c < 4; ++c) {
                float dx = col0 + (float)c - px[a];
                dx2[a][c] = dx * dx;
            }

        const float rowbase = (float)(slice * SLICE_ROWS + (tid >> 6));
        float acc[PPB] = {0.f, 0.f, 0.f, 0.f};

        #pragma unroll
        for (int k = 0; k < 8; ++k) {
            const float4 h4 = cur;
            cur = nxt;
            if (k < 6) nxt = hm4[gbase + (k + 2) * 256];   // prefetch k+2
            const float row = rowbase + (float)(4 * k);
            const float hx[4] = {h4.x, h4.y, h4.z, h4.w};
            float ct[4];
            #pragma unroll
            for (int c = 0; c < 4; ++c) ct[c] = fmaf(-hx[c], dmax, dmax); // (1-h)*dmax
            float dy2[PPB];
            #pragma unroll
            for (int a = 0; a < PPB; ++a) { float dy = row - py[a]; dy2[a] = dy * dy; }

            // 16 independent 7-op chains: add->sqrt->fma->rcp->mul->mul->fma
            #pragma unroll
            for (int a = 0; a < PPB; ++a) {
                #pragma unroll
                for (int c = 0; c < 4; ++c) {
                    float d  = __builtin_amdgcn_sqrtf(dy2[a] + dx2[a][c]);
                    float w  = fmaf(hx[c], d, ct[c]);          // hm*d + (1-hm)*dmax
                    float r  = __builtin_amdgcn_rcpf(w);
                    float r2 = r * r;
                    acc[a]   = fmaf(r2 * r2, r, acc[a]);       // += w^-5
                }
            }
        }

        // interleaved reduction: 4 independent shfl chains per round
        float v[PPB] = {acc[0], acc[1], acc[2], acc[3]};
        #pragma unroll
        for (int off = 32; off; off >>= 1) {
            #pragma unroll
            for (int a = 0; a < PPB; ++a) v[a] += __shfl_down(v[a], off, 64);
        }
        if ((tid & 63) == 0) {
            #pragma unroll
            for (int a = 0; a < PPB; ++a) sred[a][tid >> 6] = v[a];
        }
        __syncthreads();
        if (tid < PPB) {
            ws[WS_SP + (p0 + tid) * NSLICES + slice] =
                sred[tid][0] + sred[tid][1] + sred[tid][2] + sred[tid][3];
        }
    }
}

// ---------------------------------------------------------------------------
// Final combine (1 block): kernel boundary guarantees visibility of partials.
// ---------------------------------------------------------------------------
__global__ __launch_bounds__(NP) void whd_final(const float* __restrict__ ws,
                                                float* __restrict__ out) {
    const int t = threadIdx.x;  // 0..511
    const float4* w4 = (const float4*)(ws + WS_SP);
    float4 a = w4[t * 2], b = w4[t * 2 + 1];
    float S = ((a.x + a.y) + (a.z + a.w)) + ((b.x + b.y) + (b.z + b.w));
    // soft_min[p] = (S/NPIX)^(-1/5) = exp2(-0.2*log2(S/NPIX))
    float sm = exp2f(-0.2f * log2f(S * (1.f / (float)NPIX)));
    float v1 = ws[WS_T1A + t];   // NB_T1 == NP == 512: one partial per thread
    float v2 = ws[WS_T1B + t];

    #pragma unroll
    for (int off = 32; off; off >>= 1) {
        sm += __shfl_down(sm, off, 64);
        v1 += __shfl_down(v1, off, 64);
        v2 += __shfl_down(v2, off, 64);
    }
    __shared__ float red[3][8];
    if ((t & 63) == 0) { int w = t >> 6; red[0][w] = sm; red[1][w] = v1; red[2][w] = v2; }
    __syncthreads();
    if (t == 0) {
        float rsm = 0.f, r1 = 0.f, r2 = 0.f;
        #pragma unroll
        for (int w = 0; w < 8; ++w) { rsm += red[0][w]; r1 += red[1][w]; r2 += red[2][w]; }
        out[0] = r1 / r2 + rsm * (1.f / (float)NP);
    }
}

extern "C" void kernel_launch(void* const* d_in, const int* in_sizes, int n_in,
                              void* d_out, int out_size, void* d_ws, size_t ws_size,
                              hipStream_t stream) {
    const float* hm  = (const float*)d_in[0];   // (256,256) f32
    const float* pts = (const float*)d_in[1];   // (512,2)  f32
    float* ws  = (float*)d_ws;
    float* out = (float*)d_out;

    // no memset: every ws slot consumed by whd_final is written by whd_main
    whd_main <<<NB_TOTAL, 256, 0, stream>>>(hm, pts, ws);
    whd_final<<<1,        NP,  0, stream>>>(ws, out);
}

// Round 12
// 69.383 us; speedup vs baseline: 1.1646x; 1.1646x over previous
//
#include <hip/hip_runtime.h>

// Problem constants (match reference)
#define HH 256
#define WW 256
#define NPIX (HH * WW)        // 65536
#define NP 512                // points
// ALPHA = -5.0, 1/ALPHA = -0.2

// term2 decomposition: each block = 4 consecutive points x one 32-row slice
#define PPB 4
#define SLICE_ROWS 32
#define NSLICES (HH / SLICE_ROWS)          // 8
#define NPGRP (NP / PPB)                   // 128
#define NB_T2 (NPGRP * NSLICES)            // 1024
#define NB_T1 (NPIX / 256)                 // 256
#define NB_TOTAL (NB_T1 + NB_T2)           // 1280  (5 blocks/CU, all co-resident)

// ws float layout (NO memset: every slot read by final is written by main):
//   [0 .. 4096)          S-partials: ws[p*8 + slice]
//   [4096 .. 4352)       term1 v1 partials (per t1 block)
//   [4352 .. 4608)       term1 v2 partials
#define WS_SP   0
#define WS_T1A  (NP * NSLICES)             // 4096
#define WS_T1B  (WS_T1A + NB_T1)           // 4352

// launch_bounds(256, 5): 5 waves/EU minimum -> VGPR cap ~102; keeps the
// 2-deep hm prefetch live (default allocator crushed to 44 VGPRs and
// re-sank the loads into the loop). Grid is 5 blocks/CU.
// NOTE (r11 lesson): t1's point-loop index MUST stay wave-uniform so the
// compiler emits scalar s_load broadcasts; lane-dependent bases turn the
// point stream into per-lane VMEM traffic (128KB/wave) and regress 16%.
__global__ __launch_bounds__(256, 5) void whd_main(const float* __restrict__ hm,
                                                   const float* __restrict__ pts,
                                                   float* __restrict__ ws) {
    const int tid = threadIdx.x;
    const int bid = blockIdx.x;
    __shared__ float sred[PPB][4];
    __shared__ float dmax_sh;

    if (bid < NB_T1) {
        // ---------------- term 1: heat-weighted min distance ----------------
        const int idx = bid * 256 + tid;
        const float fi = (float)(idx >> 8);
        const float fj = (float)(idx & (WW - 1));
        const float4* pts4 = (const float4*)pts;   // uniform idx -> SGPR loads
        float m0 = 3.4e38f, m1 = 3.4e38f, m2 = 3.4e38f, m3 = 3.4e38f;
        #pragma unroll 4
        for (int i = 0; i < NP / 2; i += 4) {      // each float4 = 2 points (y,x)
            float4 q0 = pts4[i], q1 = pts4[i + 1], q2 = pts4[i + 2], q3 = pts4[i + 3];
            float dy, dx;
            dy = fi - q0.x; dx = fj - q0.y; m0 = fminf(m0, fmaf(dy, dy, dx * dx));
            dy = fi - q0.z; dx = fj - q0.w; m1 = fminf(m1, fmaf(dy, dy, dx * dx));
            dy = fi - q1.x; dx = fj - q1.y; m2 = fminf(m2, fmaf(dy, dy, dx * dx));
            dy = fi - q1.z; dx = fj - q1.w; m3 = fminf(m3, fmaf(dy, dy, dx * dx));
            dy = fi - q2.x; dx = fj - q2.y; m0 = fminf(m0, fmaf(dy, dy, dx * dx));
            dy = fi - q2.z; dx = fj - q2.w; m1 = fminf(m1, fmaf(dy, dy, dx * dx));
            dy = fi - q3.x; dx = fj - q3.y; m2 = fminf(m2, fmaf(dy, dy, dx * dx));
            dy = fi - q3.z; dx = fj - q3.w; m3 = fminf(m3, fmaf(dy, dy, dx * dx));
        }
        float mind = __builtin_amdgcn_sqrtf(fminf(fminf(m0, m1), fminf(m2, m3)));
        float h  = hm[idx];
        float v1 = h * mind;
        float v2 = fabsf(h);
        #pragma unroll
        for (int off = 32; off; off >>= 1) {
            v1 += __shfl_down(v1, off, 64);
            v2 += __shfl_down(v2, off, 64);
        }
        if ((tid & 63) == 0) { sred[0][tid >> 6] = v1; sred[1][tid >> 6] = v2; }
        __syncthreads();
        if (tid == 0) ws[WS_T1A + bid] = sred[0][0] + sred[0][1] + sred[0][2] + sred[0][3];
        if (tid == 1) ws[WS_T1B + bid] = sred[1][0] + sred[1][1] + sred[1][2] + sred[1][3];
    } else {
        // ---------------- term 2: soft-min accumulation ----------------
        const int b2    = bid - NB_T1;
        const int pgrp  = b2 & (NPGRP - 1);
        const int slice = b2 >> 7;             // NPGRP = 128
        const int p0    = pgrp * PPB;

        // 2-deep hm prefetch pipeline; first two issued BEFORE the dmax
        // preamble so the preamble hides their L2 latency.
        const float4* hm4 = (const float4*)hm;
        const int gbase = slice * (SLICE_ROWS * WW / 4) + tid;
        float4 cur = hm4[gbase];
        float4 nxt = hm4[gbase + 256];

        // dmax by wave 0 only (grid max is at a corner; d^2 separable)
        if (tid < 64) {
            float m = 0.f;
            #pragma unroll
            for (int t = 0; t < 8; ++t) {
                int p = tid + t * 64;
                float py_ = pts[2 * p], px_ = pts[2 * p + 1];
                float my = fmaxf(py_ * py_, (255.f - py_) * (255.f - py_));
                float mx = fmaxf(px_ * px_, (255.f - px_) * (255.f - px_));
                m = fmaxf(m, my + mx);
            }
            #pragma unroll
            for (int off = 32; off; off >>= 1) m = fmaxf(m, __shfl_down(m, off, 64));
            if (tid == 0) dmax_sh = __builtin_amdgcn_sqrtf(m);
        }
        __syncthreads();
        const float dmax = dmax_sh;

        float py[PPB], px[PPB];
        #pragma unroll
        for (int a = 0; a < PPB; ++a) {        // uniform -> SGPR loads
            py[a] = pts[2 * (p0 + a)];
            px[a] = pts[2 * (p0 + a) + 1];
        }

        // thread owns cols col0..col0+3 of rows {slice*32 + (tid>>6) + 4k}
        const float col0 = (float)((tid & 63) << 2);
        float dx2[PPB][4];
        #pragma unroll
        for (int a = 0; a < PPB; ++a)
            #pragma unroll
            for (int c = 0; c < 4; ++c) {
                float dx = col0 + (float)c - px[a];
                dx2[a][c] = dx * dx;
            }

        const float rowbase = (float)(slice * SLICE_ROWS + (tid >> 6));
        float acc[PPB] = {0.f, 0.f, 0.f, 0.f};

        #pragma unroll
        for (int k = 0; k < 8; ++k) {
            const float4 h4 = cur;
            cur = nxt;
            if (k < 6) nxt = hm4[gbase + (k + 2) * 256];   // prefetch k+2
            const float row = rowbase + (float)(4 * k);
            const float hx[4] = {h4.x, h4.y, h4.z, h4.w};
            float ct[4];
            #pragma unroll
            for (int c = 0; c < 4; ++c) ct[c] = fmaf(-hx[c], dmax, dmax); // (1-h)*dmax
            float dy2[PPB];
            #pragma unroll
            for (int a = 0; a < PPB; ++a) { float dy = row - py[a]; dy2[a] = dy * dy; }

            // 16 independent 7-op chains: add->sqrt->fma->rcp->mul->mul->fma
            #pragma unroll
            for (int a = 0; a < PPB; ++a) {
                #pragma unroll
                for (int c = 0; c < 4; ++c) {
                    float d  = __builtin_amdgcn_sqrtf(dy2[a] + dx2[a][c]);
                    float w  = fmaf(hx[c], d, ct[c]);          // hm*d + (1-hm)*dmax
                    float r  = __builtin_amdgcn_rcpf(w);
                    float r2 = r * r;
                    acc[a]   = fmaf(r2 * r2, r, acc[a]);       // += w^-5
                }
            }
        }

        // interleaved reduction: 4 independent shfl chains per round
        float v[PPB] = {acc[0], acc[1], acc[2], acc[3]};
        #pragma unroll
        for (int off = 32; off; off >>= 1) {
            #pragma unroll
            for (int a = 0; a < PPB; ++a) v[a] += __shfl_down(v[a], off, 64);
        }
        if ((tid & 63) == 0) {
            #pragma unroll
            for (int a = 0; a < PPB; ++a) sred[a][tid >> 6] = v[a];
        }
        __syncthreads();
        if (tid < PPB) {
            ws[WS_SP + (p0 + tid) * NSLICES + slice] =
                sred[tid][0] + sred[tid][1] + sred[tid][2] + sred[tid][3];
        }
    }
}

// ---------------------------------------------------------------------------
// Final combine (1 block): kernel boundary guarantees visibility of partials.
// ---------------------------------------------------------------------------
__global__ __launch_bounds__(NP) void whd_final(const float* __restrict__ ws,
                                                float* __restrict__ out) {
    const int t = threadIdx.x;  // 0..511
    const float4* w4 = (const float4*)(ws + WS_SP);
    float4 a = w4[t * 2], b = w4[t * 2 + 1];
    float S = ((a.x + a.y) + (a.z + a.w)) + ((b.x + b.y) + (b.z + b.w));
    // soft_min[p] = (S/NPIX)^(-1/5) = exp2(-0.2*log2(S/NPIX))
    float sm = exp2f(-0.2f * log2f(S * (1.f / (float)NPIX)));
    float v1 = (t < NB_T1) ? ws[WS_T1A + t] : 0.f;
    float v2 = (t < NB_T1) ? ws[WS_T1B + t] : 0.f;

    #pragma unroll
    for (int off = 32; off; off >>= 1) {
        sm += __shfl_down(sm, off, 64);
        v1 += __shfl_down(v1, off, 64);
        v2 += __shfl_down(v2, off, 64);
    }
    __shared__ float red[3][8];
    if ((t & 63) == 0) { int w = t >> 6; red[0][w] = sm; red[1][w] = v1; red[2][w] = v2; }
    __syncthreads();
    if (t == 0) {
        float rsm = 0.f, r1 = 0.f, r2 = 0.f;
        #pragma unroll
        for (int w = 0; w < 8; ++w) { rsm += red[0][w]; r1 += red[1][w]; r2 += red[2][w]; }
        out[0] = r1 / r2 + rsm * (1.f / (float)NP);
    }
}

extern "C" void kernel_launch(void* const* d_in, const int* in_sizes, int n_in,
                              void* d_out, int out_size, void* d_ws, size_t ws_size,
                              hipStream_t stream) {
    const float* hm  = (const float*)d_in[0];   // (256,256) f32
    const float* pts = (const float*)d_in[1];   // (512,2)  f32
    float* ws  = (float*)d_ws;
    float* out = (float*)d_out;

    // no memset: every ws slot consumed by whd_final is written by whd_main
    whd_main <<<NB_TOTAL, 256, 0, stream>>>(hm, pts, ws);
    whd_final<<<1,        NP,  0, stream>>>(ws, out);
}